// Round 3
// baseline (2000.918 us; speedup 1.0000x reference)
//
#include <hip/hip_runtime.h>
#include <hip/hip_bf16.h>

typedef __attribute__((ext_vector_type(8))) short bf16x8;
typedef __attribute__((ext_vector_type(4))) float f32x4;
typedef __attribute__((ext_vector_type(4))) unsigned short u16x4;
typedef __attribute__((ext_vector_type(8))) unsigned short u16x8;

#define DEVINL static __device__ __forceinline__

constexpr int BMx = 128, BNx = 128, BKx = 64;
constexpr int NTILES = 8;   // N = 1024 fixed for every GEMM in this pipeline
constexpr int KD = 1024;    // K = 1024 fixed

DEVINL unsigned short f2bf(float f) {
  union { float f; unsigned u; } a; a.f = f;
  return (unsigned short)((a.u + 0x7fffu + ((a.u >> 16) & 1u)) >> 16);  // RNE
}

typedef __attribute__((address_space(1))) const unsigned char ga_u8;
typedef __attribute__((address_space(3))) unsigned char ls_u8;

// C[M][1024] = A[M][1024] * B[1024][1024]^T   (bf16 operands, K-major "B^T" layout)
// Grid 1D, XCD-chunk swizzled; work order: z-major, then mt, nt innermost.
// MODE 0: +bias, C bf16 (projections; z always 0, flat M over the chunk)
// MODE 1: C f32 with LeakyReLU(0.1) + rnorm2[col] atomic (QK)
// MODE 2: C f32 plain (PV)
template<int MODE>
__global__ __launch_bounds__(256, 5) void gemm_bt(
    const void* __restrict__ Av, const void* __restrict__ Bv,
    const float* __restrict__ bias, void* __restrict__ Cv,
    float* __restrict__ rnorm2, int mt_per_z,
    long long sAz, long long sBz, long long sCz, long long sRz)
{
  alignas(16) __shared__ char lds[(BMx + BNx) * BKx * 2];  // 32 KiB
  char* ldsA = lds;
  char* ldsB = lds + BMx * BKx * 2;

  const int tid = threadIdx.x;
  const int lane = tid & 63;
  const int wv = tid >> 6;
  const int wm = wv >> 1, wn = wv & 1;
  const int kg = lane >> 4;
  const int ml = lane & 15;

  // XCD-chunked bijective swizzle (nwg is always a multiple of 8 here)
  const int nwg = (int)gridDim.x;
  const int bid = (int)blockIdx.x;
  const int w = (bid & 7) * (nwg >> 3) + (bid >> 3);
  const int z = w / (mt_per_z * NTILES);
  const int rem = w - z * mt_per_z * NTILES;
  const int mt = rem >> 3;
  const int nt = rem & 7;
  const int m0 = mt * BMx, n0 = nt * BNx;

  f32x4 acc[4][4];
  const f32x4 zero4 = {0.f, 0.f, 0.f, 0.f};
#pragma unroll
  for (int i = 0; i < 4; ++i)
#pragma unroll
    for (int j = 0; j < 4; ++j) acc[i][j] = zero4;

  const unsigned short* Abf = (const unsigned short*)Av + (size_t)z * (size_t)sAz;
  const unsigned short* Bbf = (const unsigned short*)Bv + (size_t)z * (size_t)sBz;

  for (int kt = 0; kt < KD / BKx; ++kt) {
    const int k0 = kt * BKx;
    // async global->LDS, width 16; LDS dest wave-uniform base + lane*16,
    // swizzle applied by permuting the GLOBAL source chunk (rule #21)
#pragma unroll
    for (int i = 0; i < 4; ++i) {
      int slot = i * 256 + tid;
      int r = slot >> 3, c = slot & 7;
      int gc = c ^ (r & 7);
      const unsigned short* gpa = Abf + (size_t)(m0 + r) * KD + k0 + gc * 8;
      const unsigned short* gpb = Bbf + (size_t)(n0 + r) * KD + k0 + gc * 8;
      char* la = ldsA + (size_t)(i * 256 + wv * 64) * 16;
      char* lb = ldsB + (size_t)(i * 256 + wv * 64) * 16;
      __builtin_amdgcn_global_load_lds((ga_u8*)gpa, (ls_u8*)la, 16, 0, 0);
      __builtin_amdgcn_global_load_lds((ga_u8*)gpb, (ls_u8*)lb, 16, 0, 0);
    }
    __syncthreads();

#pragma unroll
    for (int kk = 0; kk < BKx; kk += 32) {
      const int kb = kk * 2 + kg * 16;
      bf16x8 af[4], bfr[4];
#pragma unroll
      for (int mi = 0; mi < 4; ++mi) {
        int row = wm * 64 + mi * 16 + ml;
        af[mi] = *(const bf16x8*)(ldsA + row * (BKx * 2) + (kb ^ ((row & 7) << 4)));
      }
#pragma unroll
      for (int ni = 0; ni < 4; ++ni) {
        int row = wn * 64 + ni * 16 + ml;
        bfr[ni] = *(const bf16x8*)(ldsB + row * (BKx * 2) + (kb ^ ((row & 7) << 4)));
      }
#pragma unroll
      for (int mi = 0; mi < 4; ++mi)
#pragma unroll
        for (int ni = 0; ni < 4; ++ni)
          acc[mi][ni] = __builtin_amdgcn_mfma_f32_16x16x32_bf16(af[mi], bfr[ni], acc[mi][ni], 0, 0, 0);
    }
    __syncthreads();
  }

  // Epilogue. C/D layout: col = lane&15, row = (lane>>4)*4 + j  [m89-verified]
  if (MODE == 0) {
    unsigned short* C = (unsigned short*)Cv;
#pragma unroll
    for (int ni = 0; ni < 4; ++ni) {
      int col = n0 + wn * 64 + ni * 16 + ml;
      float bv = bias[col];
#pragma unroll
      for (int mi = 0; mi < 4; ++mi) {
        int rb = m0 + wm * 64 + mi * 16 + kg * 4;
#pragma unroll
        for (int j = 0; j < 4; ++j)
          C[(size_t)(rb + j) * 1024 + col] = f2bf(acc[mi][ni][j] + bv);
      }
    }
  } else if (MODE == 1) {
    float* C = (float*)Cv + (size_t)z * (size_t)sCz;
    float* rn = rnorm2 + (size_t)z * (size_t)sRz;
#pragma unroll
    for (int ni = 0; ni < 4; ++ni) {
      int col = n0 + wn * 64 + ni * 16 + ml;
      float cs = 0.f;
#pragma unroll
      for (int mi = 0; mi < 4; ++mi) {
        int rb = m0 + wm * 64 + mi * 16 + kg * 4;
#pragma unroll
        for (int j = 0; j < 4; ++j) {
          float v = acc[mi][ni][j];
          v = v >= 0.f ? v : 0.1f * v;   // LeakyReLU(0.1)
          C[(size_t)(rb + j) * 1024 + col] = v;
          cs += v * v;
        }
      }
      cs += __shfl_xor(cs, 16);
      cs += __shfl_xor(cs, 32);
      if (kg == 0) atomicAdd(&rn[col], cs);
    }
  } else {
    float* C = (float*)Cv + (size_t)z * (size_t)sCz;
#pragma unroll
    for (int ni = 0; ni < 4; ++ni) {
      int col = n0 + wn * 64 + ni * 16 + ml;
#pragma unroll
      for (int mi = 0; mi < 4; ++mi) {
        int rb = m0 + wm * 64 + mi * 16 + kg * 4;
#pragma unroll
        for (int j = 0; j < 4; ++j)
          C[(size_t)(rb + j) * 1024 + col] = acc[mi][ni][j];
      }
    }
  }
}

// f32 -> bf16 elementwise, 8 elems/thread, grid sized exactly (n % 2048 == 0)
__global__ __launch_bounds__(256) void cvt_bf16_k(
    const float* __restrict__ src, unsigned short* __restrict__ dst)
{
  size_t i = ((size_t)blockIdx.x * 256 + threadIdx.x) * 8;
  f32x4 x = *(const f32x4*)(src + i);
  f32x4 y = *(const f32x4*)(src + i + 4);
  union { unsigned short s[8]; u16x8 v; } u;
  u.s[0]=f2bf(x[0]); u.s[1]=f2bf(x[1]); u.s[2]=f2bf(x[2]); u.s[3]=f2bf(x[3]);
  u.s[4]=f2bf(y[0]); u.s[5]=f2bf(y[1]); u.s[6]=f2bf(y[2]); u.s[7]=f2bf(y[3]);
  *(u16x8*)(dst + i) = u.v;
}

// ctx (f32, [s][d]) -> ctxT (bf16, [d][s]) AND ctx_bf16 (bf16, [s][d])
__global__ __launch_bounds__(256) void convert_ctx_k(
    const float* __restrict__ src, unsigned short* __restrict__ dstT,
    unsigned short* __restrict__ dstR)
{
  __shared__ float tile[32][33];
  int tx = threadIdx.x & 31, ty = threadIdx.x >> 5;   // 32 x 8
  int s0 = blockIdx.x * 32, d0 = blockIdx.y * 32;
  const float* S = src + (size_t)blockIdx.z * 1024 * 1024;
  unsigned short* DT = dstT + (size_t)blockIdx.z * 1024 * 1024;
  unsigned short* DR = dstR + (size_t)blockIdx.z * 1024 * 1024;
#pragma unroll
  for (int i = 0; i < 4; ++i) {
    int s = ty + i * 8;
    float v = S[(size_t)(s0 + s) * 1024 + d0 + tx];
    tile[s][tx] = v;
    DR[(size_t)(s0 + s) * 1024 + d0 + tx] = f2bf(v);
  }
  __syncthreads();
#pragma unroll
  for (int i = 0; i < 4; ++i) {
    int d = ty + i * 8;
    DT[(size_t)(d0 + d) * 1024 + s0 + tx] = f2bf(tile[tx][d]);
  }
}

// one block per (batch-in-chunk, q): logits = smooth * S[q][s] / (sqrt(rnorm2[s])+1e-8)
// softmax over s=0..1023, output P bf16
__global__ __launch_bounds__(256) void softmax_k(
    const float* __restrict__ S, const float* __restrict__ rnorm2,
    const float* __restrict__ smoothp, unsigned short* __restrict__ P)
{
  __shared__ float shm[4], shs[4];
  const int t = threadIdx.x;
  const int z = blockIdx.x >> 9;            // QL = 512
  const float sm = *smoothp;
  f32x4 s4 = ((const f32x4*)(S + (size_t)blockIdx.x * 1024))[t];
  f32x4 r4 = ((const f32x4*)(rnorm2 + (size_t)z * 1024))[t];
  f32x4 lg;
  lg[0] = sm * s4[0] / (sqrtf(r4[0]) + 1e-8f);
  lg[1] = sm * s4[1] / (sqrtf(r4[1]) + 1e-8f);
  lg[2] = sm * s4[2] / (sqrtf(r4[2]) + 1e-8f);
  lg[3] = sm * s4[3] / (sqrtf(r4[3]) + 1e-8f);
  float mx = fmaxf(fmaxf(lg[0], lg[1]), fmaxf(lg[2], lg[3]));
#pragma unroll
  for (int o = 32; o; o >>= 1) mx = fmaxf(mx, __shfl_xor(mx, o));
  if ((t & 63) == 0) shm[t >> 6] = mx;
  __syncthreads();
  mx = fmaxf(fmaxf(shm[0], shm[1]), fmaxf(shm[2], shm[3]));
  f32x4 e;
  e[0] = __expf(lg[0] - mx); e[1] = __expf(lg[1] - mx);
  e[2] = __expf(lg[2] - mx); e[3] = __expf(lg[3] - mx);
  float sum = e[0] + e[1] + e[2] + e[3];
#pragma unroll
  for (int o = 32; o; o >>= 1) sum += __shfl_xor(sum, o);
  if ((t & 63) == 0) shs[t >> 6] = sum;
  __syncthreads();
  sum = shs[0] + shs[1] + shs[2] + shs[3];
  float inv = 1.f / sum;
  u16x4 p;
  p[0] = f2bf(e[0] * inv); p[1] = f2bf(e[1] * inv);
  p[2] = f2bf(e[2] * inv); p[3] = f2bf(e[3] * inv);
  ((u16x4*)(P + (size_t)blockIdx.x * 1024))[t] = p;
}

// one block per row of 1024: out = w / (sqrt(sum w^2) + 1e-8)
__global__ __launch_bounds__(256) void l2norm_k(
    const float* __restrict__ W, float* __restrict__ O)
{
  __shared__ float shs[4];
  const int t = threadIdx.x;
  f32x4 v = ((const f32x4*)(W + (size_t)blockIdx.x * 1024))[t];
  float ss = v[0]*v[0] + v[1]*v[1] + v[2]*v[2] + v[3]*v[3];
#pragma unroll
  for (int o = 32; o; o >>= 1) ss += __shfl_xor(ss, o);
  if ((t & 63) == 0) shs[t >> 6] = ss;
  __syncthreads();
  ss = shs[0] + shs[1] + shs[2] + shs[3];
  float inv = 1.f / (sqrtf(ss) + 1e-8f);
  f32x4 o4 = { v[0]*inv, v[1]*inv, v[2]*inv, v[3]*inv };
  ((f32x4*)(O + (size_t)blockIdx.x * 1024))[t] = o4;
}

extern "C" void kernel_launch(void* const* d_in, const int* in_sizes, int n_in,
                              void* d_out, int out_size, void* d_ws, size_t ws_size,
                              hipStream_t stream)
{
  (void)in_sizes; (void)n_in; (void)out_size;
  const float* query   = (const float*)d_in[0];  // [128][512][1024]
  const float* context = (const float*)d_in[1];  // [128][1024][1024]
  const float* Wq = (const float*)d_in[2];
  const float* bq = (const float*)d_in[3];
  const float* Wk = (const float*)d_in[4];
  const float* bk = (const float*)d_in[5];
  const float* smooth = (const float*)d_in[6];
  float* out = (float*)d_out;

  const int B = 128, QL = 512, SL = 1024, D = 1024;

  // per-batch scratch: qbf + ctxbf + ctxT + simq/P + simk + S/wc + rnorm2
  const size_t perB =
      (size_t)QL * D * 2 + (size_t)SL * D * 2 + (size_t)D * SL * 2 +
      (size_t)QL * D * 2 + (size_t)SL * D * 2 + (size_t)QL * SL * 4 +
      (size_t)SL * 4 + 2048;
  const size_t fixed = 2 * (size_t)D * D * 2 + 8192;   // wqbf + wkbf
  size_t usable = ws_size > fixed ? ws_size - fixed : 0;
  int C = (int)(usable / perB);
  if (C > B) C = B;
  if (C < 1) C = 1;

  char* p = (char*)d_ws;
  auto alloc = [&](size_t bytes) {
    char* r = p; p += (bytes + 255) & ~(size_t)255; return r;
  };
  unsigned short* wqbf = (unsigned short*)alloc((size_t)D * D * 2);
  unsigned short* wkbf = (unsigned short*)alloc((size_t)D * D * 2);
  unsigned short* qbf  = (unsigned short*)alloc((size_t)C * QL * D * 2);
  unsigned short* ctxbf= (unsigned short*)alloc((size_t)C * SL * D * 2);
  unsigned short* ctxT = (unsigned short*)alloc((size_t)C * D * SL * 2);
  unsigned short* simq = (unsigned short*)alloc((size_t)C * QL * D * 2);  // later P
  unsigned short* simk = (unsigned short*)alloc((size_t)C * SL * D * 2);
  float* Sbuf = (float*)alloc((size_t)C * QL * SL * 4);                   // later wc
  float* rn   = (float*)alloc((size_t)C * SL * 4);

  // weights: convert once (outside chunk loop; deterministic every call)
  cvt_bf16_k<<<dim3(D * D / 2048), 256, 0, stream>>>(Wq, wqbf);
  cvt_bf16_k<<<dim3(D * D / 2048), 256, 0, stream>>>(Wk, wkbf);

  for (int b0 = 0; b0 < B; b0 += C) {
    const int Cc = (B - b0) < C ? (B - b0) : C;
    hipMemsetAsync(rn, 0, (size_t)Cc * SL * 4, stream);
    // input conversions
    cvt_bf16_k<<<dim3(Cc * QL * D / 2048), 256, 0, stream>>>(
        query + (size_t)b0 * QL * D, qbf);
    convert_ctx_k<<<dim3(32, 32, Cc), 256, 0, stream>>>(
        context + (size_t)b0 * SL * D, ctxT, ctxbf);
    // projections: sim_q = query Wq^T + bq ; sim_k = ctx Wk^T + bk  (bf16 out)
    gemm_bt<0><<<dim3(Cc * 4 * NTILES), 256, 0, stream>>>(
        qbf, wqbf, bq, simq, nullptr, Cc * 4, 0, 0, 0, 0);
    gemm_bt<0><<<dim3(Cc * 8 * NTILES), 256, 0, stream>>>(
        ctxbf, wkbf, bk, simk, nullptr, Cc * 8, 0, 0, 0, 0);
    // S[q][s] = leaky(simq . simk), rnorm2[s] += sum_q leaky^2
    gemm_bt<1><<<dim3(Cc * 4 * NTILES), 256, 0, stream>>>(
        simq, simk, nullptr, Sbuf, rn, 4,
        (long long)QL * D, (long long)SL * D, (long long)QL * SL, (long long)SL);
    softmax_k<<<Cc * QL, 256, 0, stream>>>(Sbuf, rn, smooth, simq /* P */);
    // wc = P @ ctxT^T  (contraction over s)
    gemm_bt<2><<<dim3(Cc * 4 * NTILES), 256, 0, stream>>>(
        simq /* P */, ctxT, nullptr, Sbuf /* wc */, nullptr, 4,
        (long long)QL * SL, (long long)D * SL, (long long)QL * D, 0);
    l2norm_k<<<Cc * QL, 256, 0, stream>>>(Sbuf, out + (size_t)b0 * QL * D);
  }
}

// Round 4
// 1415.244 us; speedup vs baseline: 1.4138x; 1.4138x over previous
//
#include <hip/hip_runtime.h>
#include <hip/hip_bf16.h>

typedef __attribute__((ext_vector_type(8))) short bf16x8;
typedef __attribute__((ext_vector_type(4))) float f32x4;
typedef __attribute__((ext_vector_type(4))) unsigned short u16x4;
typedef __attribute__((ext_vector_type(8))) unsigned short u16x8;

#define DEVINL static __device__ __forceinline__

DEVINL unsigned short f2bf(float f) {
  union { float f; unsigned u; } a; a.f = f;
  return (unsigned short)((a.u + 0x7fffu + ((a.u >> 16) & 1u)) >> 16);  // RNE
}

typedef __attribute__((address_space(1))) const unsigned char ga_u8;
typedef __attribute__((address_space(3))) unsigned char ls_u8;

constexpr int KD = 1024;
constexpr int NT8 = KD / 64;   // 16 K-tiles

// ---------------------------------------------------------------------------
// 256x256 deep-pipelined bf16 GEMM: C[M][1024] = A[M][1024] * B[1024][1024]^T
// 8 waves (512 thr), BK=64, LDS 128KB double-buffered.
// Per K-tile: 4 phases (wave-quadrant rotation), stage t+1 A-halves @p0,
// B-halves @p1 via global_load_lds (swizzled source, rule #21), one
// vmcnt(0)+barrier at tile boundary only (loads get >=2 phases of slack).
// MODE 0: +bias, C bf16 | MODE 1: C f32 LeakyReLU + rnorm2 atomics | MODE 2: C f32
// ---------------------------------------------------------------------------

// stage half h (rows h*128..h*128+127) of matrix (0=A,1=B), K-tile kt, buffer b
#define STAGE_HT(b_, mat_, h_, kt_) do { \
    const unsigned short* src_ = (mat_) == 0 ? Az : Bz; \
    const int br_ = ((mat_) == 0 ? m0 : n0) + (h_) * 128; \
    char* dst_ = lds + (b_) * 65536 + (mat_) * 32768 + (h_) * 16384; \
    const unsigned short* g0_ = src_ + (size_t)(br_ + sr) * KD + (kt_) * 64 + gc * 8; \
    const unsigned short* g1_ = src_ + (size_t)(br_ + 64 + sr) * KD + (kt_) * 64 + gc * 8; \
    __builtin_amdgcn_global_load_lds((ga_u8*)g0_, (ls_u8*)(dst_ + (0 * 512 + wv * 64) * 16), 16, 0, 0); \
    __builtin_amdgcn_global_load_lds((ga_u8*)g1_, (ls_u8*)(dst_ + (1 * 512 + wv * 64) * 16), 16, 0, 0); \
  } while (0)

// one phase: quadrant (mq_, nh_) ds-reads, optional stage, barrier, MFMA, barrier
#define PHASE(b_, mq_, nh_, ...) do { \
    char* pA_ = lds + (b_) * 65536; \
    char* pB_ = lds + (b_) * 65536 + 32768; \
    bf16x8 af_[4][2], bf_[2][2]; \
    _Pragma("unroll") \
    for (int mi = 0; mi < 4; ++mi) { \
      int row_ = wm * 128 + (mq_) * 64 + mi * 16 + ml; \
      af_[mi][0] = *(const bf16x8*)(pA_ + row_ * 128 + coff0); \
      af_[mi][1] = *(const bf16x8*)(pA_ + row_ * 128 + coff1); \
    } \
    _Pragma("unroll") \
    for (int ni = 0; ni < 2; ++ni) { \
      int row_ = wn * 64 + (nh_) * 32 + ni * 16 + ml; \
      bf_[ni][0] = *(const bf16x8*)(pB_ + row_ * 128 + coff0); \
      bf_[ni][1] = *(const bf16x8*)(pB_ + row_ * 128 + coff1); \
    } \
    __VA_ARGS__; \
    __builtin_amdgcn_s_barrier(); \
    __builtin_amdgcn_s_setprio(1); \
    _Pragma("unroll") \
    for (int mi = 0; mi < 4; ++mi) \
    _Pragma("unroll") \
    for (int ni = 0; ni < 2; ++ni) { \
      acc[(mq_) * 4 + mi][(nh_) * 2 + ni] = __builtin_amdgcn_mfma_f32_16x16x32_bf16( \
          af_[mi][0], bf_[ni][0], acc[(mq_) * 4 + mi][(nh_) * 2 + ni], 0, 0, 0); \
      acc[(mq_) * 4 + mi][(nh_) * 2 + ni] = __builtin_amdgcn_mfma_f32_16x16x32_bf16( \
          af_[mi][1], bf_[ni][1], acc[(mq_) * 4 + mi][(nh_) * 2 + ni], 0, 0, 0); \
    } \
    __builtin_amdgcn_s_setprio(0); \
  } while (0)

template<int MODE>
__global__ __launch_bounds__(512, 2) void gemm8(
    const unsigned short* __restrict__ A, const unsigned short* __restrict__ B,
    const float* __restrict__ bias, void* __restrict__ Cv,
    float* __restrict__ rnorm2, int mtiles,
    long long sAz, long long sBz, long long sCz, long long sRz)
{
  alignas(16) __shared__ char lds[131072];  // [2 buf][A|B][256 rows * 128 B]

  const int tid = threadIdx.x;
  const int lane = tid & 63;
  const int wv = tid >> 6;        // 0..7
  const int wm = wv >> 2;         // A-half this wave computes
  const int wn = wv & 3;          // 64-col slice within N-tile
  const int kg = lane >> 4;
  const int ml = lane & 15;

  // XCD-chunked bijective swizzle (grid always a multiple of 8)
  const int nwg = (int)gridDim.x;
  const int bid = (int)blockIdx.x;
  const int w = (bid & 7) * (nwg >> 3) + (bid >> 3);
  const int bpz = mtiles * 4;
  const int z = w / bpz;
  const int rem = w - z * bpz;
  const int mt = rem >> 2, nt = rem & 3;
  const int m0 = mt * 256, n0 = nt * 256;

  const unsigned short* Az = A + (size_t)z * (size_t)sAz;
  const unsigned short* Bz = B + (size_t)z * (size_t)sBz;

  // staging thread constants: slots {tid, 512+tid} of each half-tile
  const int sr = tid >> 3;                      // local row 0..63 (j=1 adds 64)
  const int gc = (tid & 7) ^ (sr & 7);          // swizzled source chunk
  // ds_read swizzled chunk offsets for ks=0,1 (row&7 == ml&7 for fragment rows)
  const int coff0 = ((0 * 4 + kg) ^ (ml & 7)) << 4;
  const int coff1 = ((1 * 4 + kg) ^ (ml & 7)) << 4;

  f32x4 acc[8][4];
  const f32x4 zero4 = {0.f, 0.f, 0.f, 0.f};
#pragma unroll
  for (int i = 0; i < 8; ++i)
#pragma unroll
    for (int j = 0; j < 4; ++j) acc[i][j] = zero4;

  // prologue: stage all 4 half-tiles of K-tile 0 into buffer 0
  STAGE_HT(0, 0, 0, 0);
  STAGE_HT(0, 0, 1, 0);
  STAGE_HT(0, 1, 0, 0);
  STAGE_HT(0, 1, 1, 0);
  asm volatile("s_waitcnt vmcnt(0)" ::: "memory");
  __builtin_amdgcn_s_barrier();

  for (int t = 0; t < NT8; ++t) {
    const int cur = t & 1;
    const int nxt = cur ^ 1;
    const bool pf = (t + 1) < NT8;
    // p0: quadrant (0,0) + stage A halves of t+1
    PHASE(cur, 0, 0, if (pf) { STAGE_HT(nxt, 0, 0, t + 1); STAGE_HT(nxt, 0, 1, t + 1); });
    __builtin_amdgcn_s_barrier();
    // p1: quadrant (0,1) + stage B halves of t+1
    PHASE(cur, 0, 1, if (pf) { STAGE_HT(nxt, 1, 0, t + 1); STAGE_HT(nxt, 1, 1, t + 1); });
    __builtin_amdgcn_s_barrier();
    // p2: quadrant (1,0)
    PHASE(cur, 1, 0, );
    __builtin_amdgcn_s_barrier();
    // p3: quadrant (1,1); tile boundary: force own loads done, then certify
    PHASE(cur, 1, 1, );
    asm volatile("s_waitcnt vmcnt(0)" ::: "memory");
    __builtin_amdgcn_s_barrier();
  }

  // Epilogue. C/D layout: col = lane&15, row = (lane>>4)*4 + j  [m89-verified]
  if (MODE == 0) {
    unsigned short* C = (unsigned short*)Cv + (size_t)z * (size_t)sCz;
#pragma unroll
    for (int ni = 0; ni < 4; ++ni) {
      int col = n0 + wn * 64 + ni * 16 + ml;
      float bv = bias[col];
#pragma unroll
      for (int mi = 0; mi < 8; ++mi) {
        int rb = m0 + wm * 128 + mi * 16 + kg * 4;
#pragma unroll
        for (int j = 0; j < 4; ++j)
          C[(size_t)(rb + j) * 1024 + col] = f2bf(acc[mi][ni][j] + bv);
      }
    }
  } else if (MODE == 1) {
    float* C = (float*)Cv + (size_t)z * (size_t)sCz;
    float* rn = rnorm2 + (size_t)z * (size_t)sRz;
#pragma unroll
    for (int ni = 0; ni < 4; ++ni) {
      int col = n0 + wn * 64 + ni * 16 + ml;
      float cs = 0.f;
#pragma unroll
      for (int mi = 0; mi < 8; ++mi) {
        int rb = m0 + wm * 128 + mi * 16 + kg * 4;
#pragma unroll
        for (int j = 0; j < 4; ++j) {
          float v = acc[mi][ni][j];
          v = v >= 0.f ? v : 0.1f * v;   // LeakyReLU(0.1)
          C[(size_t)(rb + j) * 1024 + col] = v;
          cs += v * v;
        }
      }
      cs += __shfl_xor(cs, 16);
      cs += __shfl_xor(cs, 32);
      if (kg == 0) atomicAdd(&rn[col], cs);
    }
  } else {
    float* C = (float*)Cv + (size_t)z * (size_t)sCz;
#pragma unroll
    for (int ni = 0; ni < 4; ++ni) {
      int col = n0 + wn * 64 + ni * 16 + ml;
#pragma unroll
      for (int mi = 0; mi < 8; ++mi) {
        int rb = m0 + wm * 128 + mi * 16 + kg * 4;
#pragma unroll
        for (int j = 0; j < 4; ++j)
          C[(size_t)(rb + j) * 1024 + col] = acc[mi][ni][j];
      }
    }
  }
}

// f32 -> bf16 elementwise, 8 elems/thread (n % 2048 == 0)
__global__ __launch_bounds__(256) void cvt_bf16_k(
    const float* __restrict__ src, unsigned short* __restrict__ dst)
{
  size_t i = ((size_t)blockIdx.x * 256 + threadIdx.x) * 8;
  f32x4 x = *(const f32x4*)(src + i);
  f32x4 y = *(const f32x4*)(src + i + 4);
  union { unsigned short s[8]; u16x8 v; } u;
  u.s[0]=f2bf(x[0]); u.s[1]=f2bf(x[1]); u.s[2]=f2bf(x[2]); u.s[3]=f2bf(x[3]);
  u.s[4]=f2bf(y[0]); u.s[5]=f2bf(y[1]); u.s[6]=f2bf(y[2]); u.s[7]=f2bf(y[3]);
  *(u16x8*)(dst + i) = u.v;
}

// ctx (f32, [s][d]) -> ctxT (bf16, [d][s]) AND ctx_bf16 (bf16, [s][d])
__global__ __launch_bounds__(256) void convert_ctx_k(
    const float* __restrict__ src, unsigned short* __restrict__ dstT,
    unsigned short* __restrict__ dstR)
{
  __shared__ float tile[32][33];
  int tx = threadIdx.x & 31, ty = threadIdx.x >> 5;   // 32 x 8
  int s0 = blockIdx.x * 32, d0 = blockIdx.y * 32;
  const float* S = src + (size_t)blockIdx.z * 1024 * 1024;
  unsigned short* DT = dstT + (size_t)blockIdx.z * 1024 * 1024;
  unsigned short* DR = dstR + (size_t)blockIdx.z * 1024 * 1024;
#pragma unroll
  for (int i = 0; i < 4; ++i) {
    int s = ty + i * 8;
    float v = S[(size_t)(s0 + s) * 1024 + d0 + tx];
    tile[s][tx] = v;
    DR[(size_t)(s0 + s) * 1024 + d0 + tx] = f2bf(v);
  }
  __syncthreads();
#pragma unroll
  for (int i = 0; i < 4; ++i) {
    int d = ty + i * 8;
    DT[(size_t)(d0 + d) * 1024 + s0 + tx] = f2bf(tile[tx][d]);
  }
}

// one block per (batch-in-chunk, q): softmax over s of smooth*S/(sqrt(rn)+eps) -> P bf16
__global__ __launch_bounds__(256) void softmax_k(
    const float* __restrict__ S, const float* __restrict__ rnorm2,
    const float* __restrict__ smoothp, unsigned short* __restrict__ P)
{
  __shared__ float shm[4], shs[4];
  const int t = threadIdx.x;
  const int z = blockIdx.x >> 9;            // QL = 512
  const float sm = *smoothp;
  f32x4 s4 = ((const f32x4*)(S + (size_t)blockIdx.x * 1024))[t];
  f32x4 r4 = ((const f32x4*)(rnorm2 + (size_t)z * 1024))[t];
  f32x4 lg;
  lg[0] = sm * s4[0] / (sqrtf(r4[0]) + 1e-8f);
  lg[1] = sm * s4[1] / (sqrtf(r4[1]) + 1e-8f);
  lg[2] = sm * s4[2] / (sqrtf(r4[2]) + 1e-8f);
  lg[3] = sm * s4[3] / (sqrtf(r4[3]) + 1e-8f);
  float mx = fmaxf(fmaxf(lg[0], lg[1]), fmaxf(lg[2], lg[3]));
#pragma unroll
  for (int o = 32; o; o >>= 1) mx = fmaxf(mx, __shfl_xor(mx, o));
  if ((t & 63) == 0) shm[t >> 6] = mx;
  __syncthreads();
  mx = fmaxf(fmaxf(shm[0], shm[1]), fmaxf(shm[2], shm[3]));
  f32x4 e;
  e[0] = __expf(lg[0] - mx); e[1] = __expf(lg[1] - mx);
  e[2] = __expf(lg[2] - mx); e[3] = __expf(lg[3] - mx);
  float sum = e[0] + e[1] + e[2] + e[3];
#pragma unroll
  for (int o = 32; o; o >>= 1) sum += __shfl_xor(sum, o);
  if ((t & 63) == 0) shs[t >> 6] = sum;
  __syncthreads();
  sum = shs[0] + shs[1] + shs[2] + shs[3];
  float inv = 1.f / sum;
  u16x4 p;
  p[0] = f2bf(e[0] * inv); p[1] = f2bf(e[1] * inv);
  p[2] = f2bf(e[2] * inv); p[3] = f2bf(e[3] * inv);
  ((u16x4*)(P + (size_t)blockIdx.x * 1024))[t] = p;
}

// one block per row of 1024: out = w / (sqrt(sum w^2) + 1e-8)
__global__ __launch_bounds__(256) void l2norm_k(
    const float* __restrict__ W, float* __restrict__ O)
{
  __shared__ float shs[4];
  const int t = threadIdx.x;
  f32x4 v = ((const f32x4*)(W + (size_t)blockIdx.x * 1024))[t];
  float ss = v[0]*v[0] + v[1]*v[1] + v[2]*v[2] + v[3]*v[3];
#pragma unroll
  for (int o = 32; o; o >>= 1) ss += __shfl_xor(ss, o);
  if ((t & 63) == 0) shs[t >> 6] = ss;
  __syncthreads();
  ss = shs[0] + shs[1] + shs[2] + shs[3];
  float inv = 1.f / (sqrtf(ss) + 1e-8f);
  f32x4 o4 = { v[0]*inv, v[1]*inv, v[2]*inv, v[3]*inv };
  ((f32x4*)(O + (size_t)blockIdx.x * 1024))[t] = o4;
}

extern "C" void kernel_launch(void* const* d_in, const int* in_sizes, int n_in,
                              void* d_out, int out_size, void* d_ws, size_t ws_size,
                              hipStream_t stream)
{
  (void)in_sizes; (void)n_in; (void)out_size;
  const float* query   = (const float*)d_in[0];  // [128][512][1024]
  const float* context = (const float*)d_in[1];  // [128][1024][1024]
  const float* Wq = (const float*)d_in[2];
  const float* bq = (const float*)d_in[3];
  const float* Wk = (const float*)d_in[4];
  const float* bk = (const float*)d_in[5];
  const float* smooth = (const float*)d_in[6];
  float* out = (float*)d_out;

  const int B = 128, QL = 512, SL = 1024, D = 1024;

  // per-batch scratch: qbf + ctxbf + ctxT + simq/P + simk + S/wc + rnorm2
  const size_t perB =
      (size_t)QL * D * 2 + (size_t)SL * D * 2 + (size_t)D * SL * 2 +
      (size_t)QL * D * 2 + (size_t)SL * D * 2 + (size_t)QL * SL * 4 +
      (size_t)SL * 4 + 2048;
  const size_t fixed = 2 * (size_t)D * D * 2 + 8192;   // wqbf + wkbf
  size_t usable = ws_size > fixed ? ws_size - fixed : 0;
  int C = (int)(usable / perB);
  if (C > B) C = B;
  if (C < 1) C = 1;

  char* p = (char*)d_ws;
  auto alloc = [&](size_t bytes) {
    char* r = p; p += (bytes + 255) & ~(size_t)255; return r;
  };
  unsigned short* wqbf = (unsigned short*)alloc((size_t)D * D * 2);
  unsigned short* wkbf = (unsigned short*)alloc((size_t)D * D * 2);
  unsigned short* qbf  = (unsigned short*)alloc((size_t)C * QL * D * 2);
  unsigned short* ctxbf= (unsigned short*)alloc((size_t)C * SL * D * 2);
  unsigned short* ctxT = (unsigned short*)alloc((size_t)C * D * SL * 2);
  unsigned short* simq = (unsigned short*)alloc((size_t)C * QL * D * 2);  // later P
  unsigned short* simk = (unsigned short*)alloc((size_t)C * SL * D * 2);
  float* Sbuf = (float*)alloc((size_t)C * QL * SL * 4);                   // later wc
  float* rn   = (float*)alloc((size_t)C * SL * 4);

  // weights: convert once
  cvt_bf16_k<<<dim3(D * D / 2048), 256, 0, stream>>>(Wq, wqbf);
  cvt_bf16_k<<<dim3(D * D / 2048), 256, 0, stream>>>(Wk, wkbf);

  for (int b0 = 0; b0 < B; b0 += C) {
    const int Cc = (B - b0) < C ? (B - b0) : C;
    hipMemsetAsync(rn, 0, (size_t)Cc * SL * 4, stream);
    cvt_bf16_k<<<dim3(Cc * QL * D / 2048), 256, 0, stream>>>(
        query + (size_t)b0 * QL * D, qbf);
    convert_ctx_k<<<dim3(32, 32, Cc), 256, 0, stream>>>(
        context + (size_t)b0 * SL * D, ctxT, ctxbf);
    // projections: sim_q = q Wq^T + bq ; sim_k = ctx Wk^T + bk  (bf16 out)
    gemm8<0><<<dim3(Cc * 8), 512, 0, stream>>>(
        qbf, wqbf, bq, simq, nullptr, 2,
        (long long)QL * D, 0, (long long)QL * D, 0);
    gemm8<0><<<dim3(Cc * 16), 512, 0, stream>>>(
        ctxbf, wkbf, bk, simk, nullptr, 4,
        (long long)SL * D, 0, (long long)SL * D, 0);
    // S[q][s] = leaky(simq . simk), rnorm2[s] += sum_q leaky^2
    gemm8<1><<<dim3(Cc * 8), 512, 0, stream>>>(
        simq, simk, nullptr, Sbuf, rn, 2,
        (long long)QL * D, (long long)SL * D, (long long)QL * SL, (long long)SL);
    softmax_k<<<Cc * QL, 256, 0, stream>>>(Sbuf, rn, smooth, simq /* P */);
    // wc = P @ ctxT^T  (contraction over s)
    gemm8<2><<<dim3(Cc * 8), 512, 0, stream>>>(
        simq /* P */, ctxT, nullptr, Sbuf /* wc */, nullptr, 2,
        (long long)QL * SL, (long long)D * SL, (long long)QL * D, 0);
    l2norm_k<<<Cc * QL, 256, 0, stream>>>(Sbuf, out + (size_t)b0 * QL * D);
  }
}

// Round 5
// 1249.302 us; speedup vs baseline: 1.6016x; 1.1328x over previous
//
#include <hip/hip_runtime.h>
#include <hip/hip_bf16.h>

typedef __attribute__((ext_vector_type(8))) short bf16x8;
typedef __attribute__((ext_vector_type(4))) float f32x4;
typedef __attribute__((ext_vector_type(4))) unsigned short u16x4;
typedef __attribute__((ext_vector_type(8))) unsigned short u16x8;

#define DEVINL static __device__ __forceinline__

DEVINL unsigned short f2bf(float f) {
  union { float f; unsigned u; } a; a.f = f;
  return (unsigned short)((a.u + 0x7fffu + ((a.u >> 16) & 1u)) >> 16);  // RNE
}

typedef __attribute__((address_space(1))) const unsigned char ga_u8;
typedef __attribute__((address_space(3))) unsigned char ls_u8;

constexpr int KD = 1024;
constexpr int NKT = KD / 64;   // 16 K-tiles

// ---------------------------------------------------------------------------
// 256x256 bf16 GEMM, 8 waves (2M x 4N), BK=64, LDS 2x64KB double-buffered.
// Per K-tile: 2 K-half phases, each = {12 ds_read_b128 -> 4 global_load_lds
// stage -> 32 MFMA (setprio-wrapped)}; ONE vmcnt(0)+s_barrier per K-tile
// (stages write buf[nxt], reads hit buf[cur] -> no intra-tile hazard; waves
// free-run so MFMA of one wave hides ds_read/stage of the other).
// Both-sides XOR-16B-chunk swizzle (rule #21): pre-swizzled global source +
// swizzled ds_read offset.  Epilogue: per-wave-private LDS bounce -> full
// 128B-line global stores (fixes 1.85x write amplification seen in r4).
// MODE 0: +bias, C bf16 | MODE 1: C f32 LeakyReLU + rnorm2 atomics | MODE 2: C f32
// ---------------------------------------------------------------------------

// stage matrix (0=A rows m0.., 1=B rows n0..) of K-tile kt_ into buffer b_
#define STAGE(b_, mat_, kt_) do { \
    const unsigned short* src_ = (mat_) == 0 ? Az : Bz; \
    const int br_ = (mat_) == 0 ? m0 : n0; \
    char* dst_ = lds + (b_) * 65536 + (mat_) * 32768; \
    _Pragma("unroll") \
    for (int i_ = 0; i_ < 4; ++i_) { \
      const unsigned short* g_ = src_ + (size_t)(br_ + i_ * 64 + sr) * KD + (kt_) * 64 + gc * 8; \
      __builtin_amdgcn_global_load_lds((ga_u8*)g_, (ls_u8*)(dst_ + (i_ * 512 + wv * 64) * 16), 16, 0, 0); \
    } \
  } while (0)

// one K-half phase: full-wave fragment block (8 A + 4 B reads), stage, 32 MFMA
#define KSUB(b_, ks_, STG) do { \
    const char* pA_ = lds + (b_) * 65536; \
    const char* pB_ = pA_ + 32768; \
    const int co_ = (((ks_) * 4 + kg) ^ (ml & 7)) << 4; \
    bf16x8 af_[8], bf_[4]; \
    _Pragma("unroll") \
    for (int mi = 0; mi < 8; ++mi) \
      af_[mi] = *(const bf16x8*)(pA_ + (wm * 128 + mi * 16 + ml) * 128 + co_); \
    _Pragma("unroll") \
    for (int ni = 0; ni < 4; ++ni) \
      bf_[ni] = *(const bf16x8*)(pB_ + (wn * 64 + ni * 16 + ml) * 128 + co_); \
    STG; \
    __builtin_amdgcn_s_setprio(1); \
    _Pragma("unroll") \
    for (int mi = 0; mi < 8; ++mi) \
    _Pragma("unroll") \
    for (int ni = 0; ni < 4; ++ni) \
      acc[mi][ni] = __builtin_amdgcn_mfma_f32_16x16x32_bf16(af_[mi], bf_[ni], acc[mi][ni], 0, 0, 0); \
    __builtin_amdgcn_s_setprio(0); \
  } while (0)

template<int MODE>
__global__ __launch_bounds__(512, 2) void gemm8(
    const unsigned short* __restrict__ A, const unsigned short* __restrict__ B,
    const float* __restrict__ bias, void* __restrict__ Cv,
    float* __restrict__ rnorm2, int mtiles,
    long long sAz, long long sBz, long long sCz, long long sRz)
{
  alignas(16) __shared__ char lds[131072];  // [2 buf][A|B][256 rows * 128 B]

  const int tid = threadIdx.x;
  const int lane = tid & 63;
  const int wv = tid >> 6;        // 0..7
  const int wm = wv >> 2;         // A-half (128 rows)
  const int wn = wv & 3;          // 64-col slice
  const int kg = lane >> 4;
  const int ml = lane & 15;

  // XCD-chunked bijective swizzle (grid always a multiple of 8)
  const int nwg = (int)gridDim.x;
  const int bid = (int)blockIdx.x;
  const int w = (bid & 7) * (nwg >> 3) + (bid >> 3);
  const int bpz = mtiles * 4;
  const int z = w / bpz;
  const int rem = w - z * bpz;
  const int mt = rem >> 2, nt = rem & 3;
  const int m0 = mt * 256, n0 = nt * 256;

  const unsigned short* Az = A + (size_t)z * (size_t)sAz;
  const unsigned short* Bz = B + (size_t)z * (size_t)sBz;

  // staging constants: issue i covers rows i*64+sr, chunk gc (pre-swizzled)
  const int sr = tid >> 3;                       // 0..63
  const int gc = (tid & 7) ^ (sr & 7);

  f32x4 acc[8][4];
  const f32x4 zero4 = {0.f, 0.f, 0.f, 0.f};
#pragma unroll
  for (int i = 0; i < 8; ++i)
#pragma unroll
    for (int j = 0; j < 4; ++j) acc[i][j] = zero4;

  STAGE(0, 0, 0);
  STAGE(0, 1, 0);
  asm volatile("s_waitcnt vmcnt(0)" ::: "memory");
  __builtin_amdgcn_s_barrier();

  for (int t = 0; t < NKT; ++t) {
    const int cur = t & 1;
    const int nxt = cur ^ 1;
    if (t + 1 < NKT) {
      KSUB(cur, 0, STAGE(nxt, 0, t + 1));
      KSUB(cur, 1, STAGE(nxt, 1, t + 1));
    } else {
      KSUB(cur, 0, );
      KSUB(cur, 1, );
    }
    asm volatile("s_waitcnt vmcnt(0)" ::: "memory");
    __builtin_amdgcn_s_barrier();
  }

  // ---------------- epilogue: per-wave-private LDS bounce ----------------
  // acc layout per 16x16 frag: col = ni*16 + ml, row = kg*4 + j  [m89]
  float* ew = (float*)(lds + wv * 4352);     // [16][68] f32, private per wave
  const int erow = lane >> 3;                // 0..7
  const int ec8 = (lane & 7) * 8;            // col base 0..56
  const int ncol0 = n0 + wn * 64;

  if (MODE == 1) {  // leaky into acc + per-column sum-of-squares atomics
    float* rn = rnorm2 + (size_t)z * (size_t)sRz;
#pragma unroll
    for (int ni = 0; ni < 4; ++ni) {
      float cs = 0.f;
#pragma unroll
      for (int mi = 0; mi < 8; ++mi)
#pragma unroll
        for (int j = 0; j < 4; ++j) {
          float v = acc[mi][ni][j];
          v = v >= 0.f ? v : 0.1f * v;
          acc[mi][ni][j] = v;
          cs += v * v;
        }
      cs += __shfl_xor(cs, 16);
      cs += __shfl_xor(cs, 32);
      if (kg == 0) atomicAdd(&rn[ncol0 + ni * 16 + ml], cs);
    }
  }

  f32x4 bv0 = zero4, bv1 = zero4;
  if (MODE == 0) {
    bv0 = *(const f32x4*)(bias + ncol0 + ec8);
    bv1 = *(const f32x4*)(bias + ncol0 + ec8 + 4);
  }

#pragma unroll
  for (int mi = 0; mi < 8; ++mi) {
    // scatter fragment rows into ew (<=2-way bank alias, free)
#pragma unroll
    for (int ni = 0; ni < 4; ++ni)
#pragma unroll
      for (int j = 0; j < 4; ++j)
        ew[(kg * 4 + j) * 68 + ni * 16 + ml] = acc[mi][ni][j];
    // coalesced readback: lane covers cols ec8..ec8+7 of rows erow, erow+8
    const int rb = m0 + wm * 128 + mi * 16;
#pragma unroll
    for (int i = 0; i < 2; ++i) {
      const int r = erow + 8 * i;
      f32x4 x = *(const f32x4*)(&ew[r * 68 + ec8]);
      f32x4 y = *(const f32x4*)(&ew[r * 68 + ec8 + 4]);
      if (MODE == 0) {
        unsigned short* C = (unsigned short*)Cv + (size_t)z * (size_t)sCz;
        union { unsigned short s[8]; u16x8 v; } u;
        u.s[0]=f2bf(x[0]+bv0[0]); u.s[1]=f2bf(x[1]+bv0[1]);
        u.s[2]=f2bf(x[2]+bv0[2]); u.s[3]=f2bf(x[3]+bv0[3]);
        u.s[4]=f2bf(y[0]+bv1[0]); u.s[5]=f2bf(y[1]+bv1[1]);
        u.s[6]=f2bf(y[2]+bv1[2]); u.s[7]=f2bf(y[3]+bv1[3]);
        *(u16x8*)(C + (size_t)(rb + r) * 1024 + ncol0 + ec8) = u.v;
      } else {
        float* C = (float*)Cv + (size_t)z * (size_t)sCz;
        *(f32x4*)(C + (size_t)(rb + r) * 1024 + ncol0 + ec8) = x;
        *(f32x4*)(C + (size_t)(rb + r) * 1024 + ncol0 + ec8 + 4) = y;
      }
    }
  }
}

// f32 -> bf16 elementwise, 8 elems/thread (n % 2048 == 0)
__global__ __launch_bounds__(256) void cvt_bf16_k(
    const float* __restrict__ src, unsigned short* __restrict__ dst)
{
  size_t i = ((size_t)blockIdx.x * 256 + threadIdx.x) * 8;
  f32x4 x = *(const f32x4*)(src + i);
  f32x4 y = *(const f32x4*)(src + i + 4);
  union { unsigned short s[8]; u16x8 v; } u;
  u.s[0]=f2bf(x[0]); u.s[1]=f2bf(x[1]); u.s[2]=f2bf(x[2]); u.s[3]=f2bf(x[3]);
  u.s[4]=f2bf(y[0]); u.s[5]=f2bf(y[1]); u.s[6]=f2bf(y[2]); u.s[7]=f2bf(y[3]);
  *(u16x8*)(dst + i) = u.v;
}

// ctx (f32, [s][d]) -> ctxT (bf16, [d][s]) AND ctx_bf16 (bf16, [s][d])
__global__ __launch_bounds__(256) void convert_ctx_k(
    const float* __restrict__ src, unsigned short* __restrict__ dstT,
    unsigned short* __restrict__ dstR)
{
  __shared__ float tile[32][33];
  int tx = threadIdx.x & 31, ty = threadIdx.x >> 5;   // 32 x 8
  int s0 = blockIdx.x * 32, d0 = blockIdx.y * 32;
  const float* S = src + (size_t)blockIdx.z * 1024 * 1024;
  unsigned short* DT = dstT + (size_t)blockIdx.z * 1024 * 1024;
  unsigned short* DR = dstR + (size_t)blockIdx.z * 1024 * 1024;
#pragma unroll
  for (int i = 0; i < 4; ++i) {
    int s = ty + i * 8;
    float v = S[(size_t)(s0 + s) * 1024 + d0 + tx];
    tile[s][tx] = v;
    DR[(size_t)(s0 + s) * 1024 + d0 + tx] = f2bf(v);
  }
  __syncthreads();
#pragma unroll
  for (int i = 0; i < 4; ++i) {
    int d = ty + i * 8;
    DT[(size_t)(d0 + d) * 1024 + s0 + tx] = f2bf(tile[tx][d]);
  }
}

// one block per (batch-in-chunk, q): softmax over s of smooth*S/(sqrt(rn)+eps) -> P bf16
__global__ __launch_bounds__(256) void softmax_k(
    const float* __restrict__ S, const float* __restrict__ rnorm2,
    const float* __restrict__ smoothp, unsigned short* __restrict__ P)
{
  __shared__ float shm[4], shs[4];
  const int t = threadIdx.x;
  const int z = blockIdx.x >> 9;            // QL = 512
  const float sm = *smoothp;
  f32x4 s4 = ((const f32x4*)(S + (size_t)blockIdx.x * 1024))[t];
  f32x4 r4 = ((const f32x4*)(rnorm2 + (size_t)z * 1024))[t];
  f32x4 lg;
  lg[0] = sm * s4[0] / (sqrtf(r4[0]) + 1e-8f);
  lg[1] = sm * s4[1] / (sqrtf(r4[1]) + 1e-8f);
  lg[2] = sm * s4[2] / (sqrtf(r4[2]) + 1e-8f);
  lg[3] = sm * s4[3] / (sqrtf(r4[3]) + 1e-8f);
  float mx = fmaxf(fmaxf(lg[0], lg[1]), fmaxf(lg[2], lg[3]));
#pragma unroll
  for (int o = 32; o; o >>= 1) mx = fmaxf(mx, __shfl_xor(mx, o));
  if ((t & 63) == 0) shm[t >> 6] = mx;
  __syncthreads();
  mx = fmaxf(fmaxf(shm[0], shm[1]), fmaxf(shm[2], shm[3]));
  f32x4 e;
  e[0] = __expf(lg[0] - mx); e[1] = __expf(lg[1] - mx);
  e[2] = __expf(lg[2] - mx); e[3] = __expf(lg[3] - mx);
  float sum = e[0] + e[1] + e[2] + e[3];
#pragma unroll
  for (int o = 32; o; o >>= 1) sum += __shfl_xor(sum, o);
  if ((t & 63) == 0) shs[t >> 6] = sum;
  __syncthreads();
  sum = shs[0] + shs[1] + shs[2] + shs[3];
  float inv = 1.f / sum;
  u16x4 p;
  p[0] = f2bf(e[0] * inv); p[1] = f2bf(e[1] * inv);
  p[2] = f2bf(e[2] * inv); p[3] = f2bf(e[3] * inv);
  ((u16x4*)(P + (size_t)blockIdx.x * 1024))[t] = p;
}

// one block per row of 1024: out = w / (sqrt(sum w^2) + 1e-8)
__global__ __launch_bounds__(256) void l2norm_k(
    const float* __restrict__ W, float* __restrict__ O)
{
  __shared__ float shs[4];
  const int t = threadIdx.x;
  f32x4 v = ((const f32x4*)(W + (size_t)blockIdx.x * 1024))[t];
  float ss = v[0]*v[0] + v[1]*v[1] + v[2]*v[2] + v[3]*v[3];
#pragma unroll
  for (int o = 32; o; o >>= 1) ss += __shfl_xor(ss, o);
  if ((t & 63) == 0) shs[t >> 6] = ss;
  __syncthreads();
  ss = shs[0] + shs[1] + shs[2] + shs[3];
  float inv = 1.f / (sqrtf(ss) + 1e-8f);
  f32x4 o4 = { v[0]*inv, v[1]*inv, v[2]*inv, v[3]*inv };
  ((f32x4*)(O + (size_t)blockIdx.x * 1024))[t] = o4;
}

extern "C" void kernel_launch(void* const* d_in, const int* in_sizes, int n_in,
                              void* d_out, int out_size, void* d_ws, size_t ws_size,
                              hipStream_t stream)
{
  (void)in_sizes; (void)n_in; (void)out_size;
  const float* query   = (const float*)d_in[0];  // [128][512][1024]
  const float* context = (const float*)d_in[1];  // [128][1024][1024]
  const float* Wq = (const float*)d_in[2];
  const float* bq = (const float*)d_in[3];
  const float* Wk = (const float*)d_in[4];
  const float* bk = (const float*)d_in[5];
  const float* smooth = (const float*)d_in[6];
  float* out = (float*)d_out;

  const int B = 128, QL = 512, SL = 1024, D = 1024;

  // per-batch scratch: qbf + ctxbf + ctxT + simq/P + simk + S/wc + rnorm2
  const size_t perB =
      (size_t)QL * D * 2 + (size_t)SL * D * 2 + (size_t)D * SL * 2 +
      (size_t)QL * D * 2 + (size_t)SL * D * 2 + (size_t)QL * SL * 4 +
      (size_t)SL * 4 + 2048;
  const size_t fixed = 2 * (size_t)D * D * 2 + 8192;   // wqbf + wkbf
  size_t usable = ws_size > fixed ? ws_size - fixed : 0;
  int C = (int)(usable / perB);
  if (C > B) C = B;
  if (C < 1) C = 1;

  char* p = (char*)d_ws;
  auto alloc = [&](size_t bytes) {
    char* r = p; p += (bytes + 255) & ~(size_t)255; return r;
  };
  unsigned short* wqbf = (unsigned short*)alloc((size_t)D * D * 2);
  unsigned short* wkbf = (unsigned short*)alloc((size_t)D * D * 2);
  unsigned short* qbf  = (unsigned short*)alloc((size_t)C * QL * D * 2);
  unsigned short* ctxbf= (unsigned short*)alloc((size_t)C * SL * D * 2);
  unsigned short* ctxT = (unsigned short*)alloc((size_t)C * D * SL * 2);
  unsigned short* simq = (unsigned short*)alloc((size_t)C * QL * D * 2);  // later P
  unsigned short* simk = (unsigned short*)alloc((size_t)C * SL * D * 2);
  float* Sbuf = (float*)alloc((size_t)C * QL * SL * 4);                   // later wc
  float* rn   = (float*)alloc((size_t)C * SL * 4);

  // weights: convert once
  cvt_bf16_k<<<dim3(D * D / 2048), 256, 0, stream>>>(Wq, wqbf);
  cvt_bf16_k<<<dim3(D * D / 2048), 256, 0, stream>>>(Wk, wkbf);

  for (int b0 = 0; b0 < B; b0 += C) {
    const int Cc = (B - b0) < C ? (B - b0) : C;
    hipMemsetAsync(rn, 0, (size_t)Cc * SL * 4, stream);
    cvt_bf16_k<<<dim3(Cc * QL * D / 2048), 256, 0, stream>>>(
        query + (size_t)b0 * QL * D, qbf);
    convert_ctx_k<<<dim3(32, 32, Cc), 256, 0, stream>>>(
        context + (size_t)b0 * SL * D, ctxT, ctxbf);
    // projections: sim_q = q Wq^T + bq ; sim_k = ctx Wk^T + bk  (bf16 out)
    gemm8<0><<<dim3(Cc * 8), 512, 0, stream>>>(
        qbf, wqbf, bq, simq, nullptr, 2,
        (long long)QL * D, 0, (long long)QL * D, 0);
    gemm8<0><<<dim3(Cc * 16), 512, 0, stream>>>(
        ctxbf, wkbf, bk, simk, nullptr, 4,
        (long long)SL * D, 0, (long long)SL * D, 0);
    // S[q][s] = leaky(simq . simk), rnorm2[s] += sum_q leaky^2
    gemm8<1><<<dim3(Cc * 8), 512, 0, stream>>>(
        simq, simk, nullptr, Sbuf, rn, 2,
        (long long)QL * D, (long long)SL * D, (long long)QL * SL, (long long)SL);
    softmax_k<<<Cc * QL, 256, 0, stream>>>(Sbuf, rn, smooth, simq /* P */);
    // wc = P @ ctxT^T  (contraction over s)
    gemm8<2><<<dim3(Cc * 8), 512, 0, stream>>>(
        simq /* P */, ctxT, nullptr, Sbuf /* wc */, nullptr, 2,
        (long long)QL * SL, (long long)D * SL, (long long)QL * D, 0);
    l2norm_k<<<Cc * QL, 256, 0, stream>>>(Sbuf, out + (size_t)b0 * QL * D);
  }
}